// Round 13
// baseline (2323.283 us; speedup 1.0000x reference)
//
#include <hip/hip_runtime.h>
#include <hip/hip_bf16.h>
#include <math.h>

typedef __hip_bfloat16 bf16;
typedef __attribute__((ext_vector_type(8))) short s8v;
typedef __attribute__((ext_vector_type(4))) float f4v;

// Problem constants (MambaEncoder: L=2, B=2, S=1024, D=512) — f32 in, f32 out.
#define B_ 2
#define S_ 1024
#define D_ 512
#define DH_ 256
#define DI_ 512
#define N_ 16
#define M_ 2048
#define M2_ 4096
#define T_ 16     // scan chunk length (register-preloaded)
#define CN_ 64    // chunks per sequence
#define NCP_ 640  // combined dt|B|C GEMM N (512 dt + 16 B + 16 C + 96 pad)
#define NB_ 512   // persistent grid blocks (2/CU guaranteed by launch_bounds)

#define IPW_N (2*512*512)
#define INW_N (4*1024*256)
#define OUTW_N (4*256*512)
#define OPW_N (2*512*512)
#define PREP_R0 ((IPW_N+INW_N+OUTW_N+OPW_N)/4)
#define PREP_R1 (4*NCP_*512)
#define PREP_R2 ((M_*D_)/4)
#define PREP_TOT (PREP_R0+PREP_R1+PREP_R2)

__device__ __forceinline__ float softplus_fast(float v) {
  return (v > 15.f) ? v : __logf(1.f + __expf(v));
}

// ---------------------------------------------------------------------------
// Distributed grid barrier (slot idx). 64 arrival lines (<=8 RMWs each, in
// parallel) + wave-0 polls one line per lane with a shfl-reduce. Counters
// zeroed by hipMemsetAsync each call. Bounded spin as a hang valve.
__device__ __forceinline__ void gsync(unsigned* bar, int idx) {
  __syncthreads();
  unsigned* base = bar + (size_t)idx * 1024;   // 64 lines x 16 unsigned
  const int tid = threadIdx.x;
  if (tid == 0) {
    __threadfence();
    __hip_atomic_fetch_add(base + (blockIdx.x & 63) * 16, 1u,
                           __ATOMIC_RELEASE, __HIP_MEMORY_SCOPE_AGENT);
  }
  if (tid < 64) {
    for (long it = 0; it < (1L << 20); ++it) {
      unsigned sum = __hip_atomic_load(base + tid * 16, __ATOMIC_ACQUIRE,
                                       __HIP_MEMORY_SCOPE_AGENT);
#pragma unroll
      for (int off = 32; off >= 1; off >>= 1) sum += __shfl_xor(sum, off, 64);
      if (sum >= (unsigned)NB_) break;
      __builtin_amdgcn_s_sleep(2);
    }
  }
  __threadfence();
  __syncthreads();
}

// ---------------------------------------------------------------------------
// Phase bodies (verbatim from the proven standalone kernels).

__device__ __forceinline__ void prep_item(
    int i,
    const float* ipW, const float* inW, const float* outW, const float* opW,
    const float* dtW, const float* xprojW, const float* x,
    bf16* ipWb, bf16* inWb, bf16* outWb, bf16* opWb, bf16* Wcomb, bf16* xb) {
  if (i < PREP_R0) {
    int e = i * 4;
    const float* s; bf16* dst; int off;
    if (e < IPW_N)                       { s = ipW;  dst = ipWb;  off = e; }
    else if (e < IPW_N + INW_N)          { s = inW;  dst = inWb;  off = e - IPW_N; }
    else if (e < IPW_N + INW_N + OUTW_N) { s = outW; dst = outWb; off = e - IPW_N - INW_N; }
    else                                 { s = opW;  dst = opWb;  off = e - IPW_N - INW_N - OUTW_N; }
    float4 v = *(const float4*)&s[off];
    dst[off + 0] = __float2bfloat16(v.x);
    dst[off + 1] = __float2bfloat16(v.y);
    dst[off + 2] = __float2bfloat16(v.z);
    dst[off + 3] = __float2bfloat16(v.w);
  } else if (i < PREP_R0 + PREP_R1) {
    int idx = i - PREP_R0;
    int k = idx & 511;
    int row = (idx >> 9) % NCP_;
    int wi = idx / (NCP_ * 512);
    float v = 0.f;
    if (row < 512) {
      const float* dw = dtW + (size_t)wi * 512 * 16 + row * 16;
      const float* xw = xprojW + (size_t)wi * 48 * 512;
#pragma unroll
      for (int r = 0; r < 16; r++) v += dw[r] * xw[r * 512 + k];
    } else if (row < 544) {
      v = xprojW[(size_t)wi * 48 * 512 + (16 + row - 512) * 512 + k];
    }
    Wcomb[idx] = __float2bfloat16(v);
  } else if (i < PREP_TOT) {
    int e = (i - PREP_R0 - PREP_R1) * 4;
    float4 v = *(const float4*)&x[e];
    xb[e + 0] = __float2bfloat16(v.x);
    xb[e + 1] = __float2bfloat16(v.y);
    xb[e + 2] = __float2bfloat16(v.z);
    xb[e + 3] = __float2bfloat16(v.w);
  }
}

// 64x64 GEMM tile. ep0: +bias/+res; ep3: ip+split(flip); ep4: op+concat.
__device__ __forceinline__ void gemm64_tile(
    const bf16* A, const float* Af, const bf16* W, long Wstr,
    const float* bias, int bstr, const float* res,
    float* C, bf16* Cb, int ldc, int K, int ep, int bm, int bn,
    short (*As)[40], short (*Ws)[40]) {
  const int seg = bm >> 11;
  const bf16* Wp = W + (size_t)seg * Wstr;
  const float* bp = bias ? bias + (size_t)seg * bstr : nullptr;
  const int tid = threadIdx.x;
  const int wave = tid >> 6, lane = tid & 63;
  const int q = lane >> 4, l15 = lane & 15;
  const int trow = tid >> 2, tcol = (tid & 3) * 8;

  f4v acc[4];
#pragma unroll
  for (int s = 0; s < 4; s++) acc[s] = (f4v){0.f, 0.f, 0.f, 0.f};

  for (int k0 = 0; k0 < K; k0 += 32) {
    if (ep == 4) {
      int ck = k0 + tcol;
      const float* src = (ck < 256)
          ? Af + (size_t)(bm + trow) * 256 + ck
          : Af + (size_t)M_ * 256 + (size_t)((bm + trow) ^ 1023) * 256 + (ck - 256);
      float4 f0 = *(const float4*)src;
      float4 f1 = *(const float4*)(src + 4);
      float fv[8] = {f0.x, f0.y, f0.z, f0.w, f1.x, f1.y, f1.z, f1.w};
      short tmp[8];
#pragma unroll
      for (int i = 0; i < 8; i++) {
        bf16 b = __float2bfloat16(fv[i]);
        tmp[i] = *(short*)&b;
      }
      *(uint4*)&As[trow][tcol] = *(uint4*)tmp;
    } else {
      *(uint4*)&As[trow][tcol] = *(const uint4*)&A[(size_t)(bm + trow) * K + k0 + tcol];
    }
    *(uint4*)&Ws[trow][tcol] = *(const uint4*)&Wp[(size_t)(bn + trow) * K + k0 + tcol];
    __syncthreads();
    s8v bfrag = *(const s8v*)&Ws[wave * 16 + l15][q * 8];
#pragma unroll
    for (int s = 0; s < 4; s++) {
      s8v afrag = *(const s8v*)&As[s * 16 + l15][q * 8];
      acc[s] = __builtin_amdgcn_mfma_f32_16x16x32_bf16(afrag, bfrag, acc[s], 0, 0, 0);
    }
    __syncthreads();
  }
  const int col = bn + wave * 16 + l15;
#pragma unroll
  for (int s = 0; s < 4; s++) {
#pragma unroll
    for (int r = 0; r < 4; r++) {
      int row = bm + s * 16 + q * 4 + r;
      float v = acc[s][r];
      if (ep == 0) {
        if (bp) v += bp[col];
        if (res) v += res[(size_t)row * ldc + col];
        C[(size_t)row * ldc + col] = v;
      } else if (ep == 3) {
        v += bp[col];
        if (col < 256)
          C[(size_t)row * 256 + col] = v;
        else
          C[(size_t)M_ * 256 + (size_t)(row ^ 1023) * 256 + (col - 256)] = v;
      } else {  // ep4
        v += bp[col];
        C[(size_t)row * 512 + col] = v;
        Cb[(size_t)row * 512 + col] = __float2bfloat16(v);
      }
    }
  }
}

// 64x128 GEMM tile. ep1: bf16 out; ep2: softplus(dt)|B|C.
__device__ __forceinline__ void mgX_tile(
    const bf16* A, const bf16* W, long Wstr,
    const float* bias, int bstr,
    float* C, bf16* Cb, int ldc, int K, int ep, int bm, int bn,
    short (*As)[40], short (*Ws)[40]) {
  const int seg = bm >> 11;
  const bf16* Wp = W + (size_t)seg * Wstr;
  const float* bp = bias ? bias + (size_t)seg * bstr : nullptr;
  const int tid = threadIdx.x;
  const int wave = tid >> 6, lane = tid & 63;
  const int q = lane >> 4, l15 = lane & 15;
  const int wc = wave * 32;
  const int arow = tid >> 2, acol = (tid & 3) * 8;
  const int wrow = tid >> 1, wcol = (tid & 1) * 16;

  f4v acc[4][2];
#pragma unroll
  for (int s = 0; s < 4; s++)
#pragma unroll
    for (int j = 0; j < 2; j++) acc[s][j] = (f4v){0.f, 0.f, 0.f, 0.f};

  for (int k0 = 0; k0 < K; k0 += 32) {
    *(uint4*)&As[arow][acol] = *(const uint4*)&A[(size_t)(bm + arow) * K + k0 + acol];
    const bf16* wsrc = &Wp[(size_t)(bn + wrow) * K + k0 + wcol];
    *(uint4*)&Ws[wrow][wcol] = *(const uint4*)wsrc;
    *(uint4*)&Ws[wrow][wcol + 8] = *(const uint4*)(wsrc + 8);
    __syncthreads();
    s8v af[4], bf[2];
#pragma unroll
    for (int s = 0; s < 4; s++) af[s] = *(const s8v*)&As[s * 16 + l15][q * 8];
#pragma unroll
    for (int j = 0; j < 2; j++) bf[j] = *(const s8v*)&Ws[wc + j * 16 + l15][q * 8];
#pragma unroll
    for (int s = 0; s < 4; s++)
#pragma unroll
      for (int j = 0; j < 2; j++)
        acc[s][j] = __builtin_amdgcn_mfma_f32_16x16x32_bf16(af[s], bf[j], acc[s][j], 0, 0, 0);
    __syncthreads();
  }
#pragma unroll
  for (int j = 0; j < 2; j++) {
    int col = bn + wc + j * 16 + l15;
#pragma unroll
    for (int s = 0; s < 4; s++) {
      int row0 = bm + s * 16 + q * 4;
#pragma unroll
      for (int r = 0; r < 4; r++) {
        float v = acc[s][j][r];
        if (ep == 1) {
          Cb[(size_t)(row0 + r) * ldc + col] = __float2bfloat16(v);
        } else {
          if (col < 512) v = softplus_fast(v + bp[col]);
          C[(size_t)(row0 + r) * ldc + col] = v;
        }
      }
    }
  }
}

// One LayerNorm row (256 threads cooperate).
__device__ __forceinline__ void ln_row(
    int row, const float* X, const float* g, const float* bta, int gstr,
    void* Y, int C, int out_bf16, float* r1, float* r2) {
  const int sel = (row >= M_) ? gstr : 0;
  const float* xr = X + (size_t)row * C;
  const int tid = threadIdx.x;
  const int per = C >> 8;
  float vals[2];
  float sum = 0.f, sumsq = 0.f;
  for (int i = 0; i < per; i++) {
    float v = xr[tid + i * 256];
    vals[i] = v;
    sum += v;
    sumsq += v * v;
  }
#pragma unroll
  for (int off = 1; off < 64; off <<= 1) {
    sum += __shfl_xor(sum, off, 64);
    sumsq += __shfl_xor(sumsq, off, 64);
  }
  int wid = tid >> 6, lane = tid & 63;
  if (lane == 0) { r1[wid] = sum; r2[wid] = sumsq; }
  __syncthreads();
  if (tid == 0) {
    float a = 0.f, c2 = 0.f;
    for (int w = 0; w < 4; w++) { a += r1[w]; c2 += r2[w]; }
    r1[0] = a; r2[0] = c2;
  }
  __syncthreads();
  float mean = r1[0] / (float)C;
  float var = r2[0] / (float)C - mean * mean;
  float rstd = rsqrtf(var + 1e-5f);
  __syncthreads();
  for (int i = 0; i < per; i++) {
    int c = tid + i * 256;
    float y = (vals[i] - mean) * rstd * g[sel + c] + bta[sel + c];
    if (out_bf16)
      ((bf16*)Y)[(size_t)row * C + c] = __float2bfloat16(y);
    else
      ((float*)Y)[(size_t)row * C + c] = y;
  }
}

__device__ __forceinline__ void conv_item(
    int idx, const bf16* xz, const float* convW, const float* convB,
    bf16* outb) {
  int d = idx & (DI_ - 1);
  int row = idx >> 9;
  int seg = row >> 11;
  int t = row & (S_ - 1);
  const float* w = convW + seg * DI_ * 4;
  float acc = convB[seg * DI_ + d];
#pragma unroll
  for (int k = 0; k < 4; k++) {
    int dt_ = k - 3;
    if (t + dt_ >= 0)
      acc += w[d * 4 + k] * __bfloat162float(xz[(size_t)(row + dt_) * 1024 + d]);
  }
  float s = acc / (1.f + __expf(-acc));
  outb[idx] = __float2bfloat16(s);
}

__device__ __forceinline__ void scanA_block(
    int blk, const float* dtbc, const bf16* xcb, const float* A_log,
    float* P, float* hend, float (*Bs)[16]) {
  const int half = blk & 1;
  const int c = (blk >> 1) & (CN_ - 1);
  const int s = blk >> 7;
  const int dir = s >> 1;
  const int d = half * 256 + threadIdx.x;
  const int r0 = s * S_ + c * T_;
  for (int i = threadIdx.x; i < T_ * 16; i += 256) {
    int t = i >> 4, n = i & 15;
    Bs[t][n] = dtbc[(size_t)(r0 + t) * NCP_ + 512 + n];
  }
  float Av[16];
#pragma unroll
  for (int n = 0; n < 16; n++) Av[n] = -__expf(A_log[dir * DI_ * 16 + d * 16 + n]);
  float dtv[T_], xv[T_];
#pragma unroll
  for (int t = 0; t < T_; t++) {
    size_t row = (size_t)(r0 + t);
    dtv[t] = dtbc[row * NCP_ + d];
    xv[t]  = __bfloat162float(xcb[row * 512 + d]);
  }
  __syncthreads();
  float h[16], Pr[16];
#pragma unroll
  for (int n = 0; n < 16; n++) { h[n] = 0.f; Pr[n] = 1.f; }
#pragma unroll
  for (int t = 0; t < T_; t++) {
    float dtx = dtv[t] * xv[t];
#pragma unroll
    for (int n = 0; n < 16; n++) {
      float a = __expf(dtv[t] * Av[n]);
      h[n] = a * h[n] + dtx * Bs[t][n];
      Pr[n] *= a;
    }
  }
  size_t base = (((size_t)s * CN_ + c) * 16) * 512 + d;
#pragma unroll
  for (int n = 0; n < 16; n++) {
    P[base + (size_t)n * 512] = Pr[n];
    hend[base + (size_t)n * 512] = h[n];
  }
  __syncthreads();
}

__device__ __forceinline__ void scanB_item(
    int idx, const float* P, const float* hend, float* Hinit) {
  int d = idx & 511;
  int n = (idx >> 9) & 15;
  int s = idx >> 13;
  float H = 0.f;
  for (int c = 0; c < CN_; c++) {
    size_t o = (((size_t)s * CN_ + c) * 16 + n) * 512 + d;
    float p = P[o];
    float he = hend[o];
    Hinit[o] = H;
    H = p * H + he;
  }
}

__device__ __forceinline__ void scanC_block(
    int blk, const float* dtbc, const bf16* xz, const bf16* xcb,
    const float* A_log, const float* Dp, const float* Hinit, bf16* ybf,
    float (*Bs)[16], float (*Cs)[16]) {
  const int half = blk & 1;
  const int c = (blk >> 1) & (CN_ - 1);
  const int s = blk >> 7;
  const int dir = s >> 1;
  const int d = half * 256 + threadIdx.x;
  const int r0 = s * S_ + c * T_;
  for (int i = threadIdx.x; i < T_ * 16; i += 256) {
    int t = i >> 4, n = i & 15;
    size_t ro = (size_t)(r0 + t) * NCP_;
    Bs[t][n] = dtbc[ro + 512 + n];
    Cs[t][n] = dtbc[ro + 528 + n];
  }
  float Av[16];
#pragma unroll
  for (int n = 0; n < 16; n++) Av[n] = -__expf(A_log[dir * DI_ * 16 + d * 16 + n]);
  float Dd = Dp[dir * DI_ + d];
  float dtv[T_], xv[T_], zv[T_];
#pragma unroll
  for (int t = 0; t < T_; t++) {
    size_t row = (size_t)(r0 + t);
    dtv[t] = dtbc[row * NCP_ + d];
    xv[t]  = __bfloat162float(xcb[row * 512 + d]);
    zv[t]  = __bfloat162float(xz[row * 1024 + 512 + d]);
  }
  float h[16];
  size_t hbase = (((size_t)s * CN_ + c) * 16) * 512 + d;
#pragma unroll
  for (int n = 0; n < 16; n++) h[n] = Hinit[hbase + (size_t)n * 512];
  __syncthreads();
#pragma unroll
  for (int t = 0; t < T_; t++) {
    float dtx = dtv[t] * xv[t];
    float acc = 0.f;
#pragma unroll
    for (int n = 0; n < 16; n++) {
      float a = __expf(dtv[t] * Av[n]);
      h[n] = a * h[n] + dtx * Bs[t][n];
      acc += h[n] * Cs[t][n];
    }
    float sil = zv[t] / (1.f + __expf(-zv[t]));
    ybf[(size_t)(r0 + t) * 512 + d] = __float2bfloat16((acc + xv[t] * Dd) * sil);
  }
  __syncthreads();
}

// ---------------------------------------------------------------------------
// The megakernel: all phases, separated by distributed grid barriers.
__global__ __launch_bounds__(256, 2) void k_mega(
    const float* x, const float* ln_g, const float* ln_b,
    const float* inW, const float* convW, const float* convB,
    const float* xprojW, const float* dtW, const float* dtB,
    const float* A_log, const float* Dp, const float* outW,
    const float* ipW, const float* ipB, const float* opW, const float* opB,
    const float* fln_g, const float* fln_b, float* out,
    float* h_cur, float* u_f, float* dtbc2, float* Pbuf, float* hend,
    bf16* xz2b, bf16* xb, bf16* xnb2, bf16* xcvb2, bf16* ybf2,
    bf16* ipWb, bf16* inWb, bf16* outWb, bf16* opWb, bf16* Wcomb,
    unsigned* bar) {
  __shared__ short As[64][40];
  __shared__ short Ws[128][40];
  __shared__ float Bs[16][16], Cs[16][16];
  __shared__ float r1[4], r2[4];
  float* Hinit = Pbuf;
  int bi = 0;
  const int gtid = blockIdx.x * 256 + threadIdx.x;

  // P0: prep
  for (int i = gtid; i < PREP_TOT; i += NB_ * 256)
    prep_item(i, ipW, inW, outW, opW, dtW, xprojW, x,
              ipWb, inWb, outWb, opWb, Wcomb, xb);
  gsync(bar, bi++);

  for (int li = 0; li < 2; li++) {
    // P1: ip + split (256 tiles)
    for (int t = blockIdx.x; t < 256; t += NB_)
      gemm64_tile(xb, nullptr, ipWb + (size_t)li * D_ * D_, 0,
                  ipB + (size_t)li * D_, 0, nullptr, u_f, nullptr, 256, D_, 3,
                  (t >> 3) * 64, (t & 7) * 64, As, (short(*)[40])Ws);
    gsync(bar, bi++);
    // P2: LN (4096 rows)
    for (int row = blockIdx.x; row < M2_; row += NB_)
      ln_row(row, u_f, ln_g + li * 2 * DH_, ln_b + li * 2 * DH_, DH_,
             (void*)xnb2, DH_, 1, r1, r2);
    gsync(bar, bi++);
    // P3: in-proj (512 tiles, 64x128)
    for (int t = blockIdx.x; t < 512; t += NB_)
      mgX_tile(xnb2, inWb + (size_t)li * 2 * 1024 * DH_, (long)1024 * DH_,
               nullptr, 0, nullptr, xz2b, 1024, DH_, 1,
               (t >> 3) * 64, (t & 7) * 128, As, Ws);
    gsync(bar, bi++);
    // P4: conv + silu
    for (int i = gtid; i < M2_ * DI_; i += NB_ * 256)
      conv_item(i, xz2b, convW + li * 2 * DI_ * 4, convB + li * 2 * DI_, xcvb2);
    gsync(bar, bi++);
    // P5: dtbc (320 tiles, 64x128)
    for (int t = blockIdx.x; t < 320; t += NB_)
      mgX_tile(xcvb2, Wcomb + (size_t)li * 2 * NCP_ * 512, (long)NCP_ * 512,
               dtB + li * 2 * DI_, DI_, dtbc2, nullptr, NCP_, 512, 2,
               (t / 5) * 64, (t % 5) * 128, As, Ws);
    gsync(bar, bi++);
    // P6: scanA (512 virtual blocks)
    for (int v = blockIdx.x; v < 512; v += NB_)
      scanA_block(v, dtbc2, xcvb2, A_log + (size_t)li * 2 * DI_ * N_,
                  Pbuf, hend, Bs);
    gsync(bar, bi++);
    // P7: scanB (32768 items)
    for (int i = gtid; i < 4 * 16 * 512; i += NB_ * 256)
      scanB_item(i, Pbuf, hend, Hinit);
    gsync(bar, bi++);
    // P8: scanC (512 virtual blocks)
    for (int v = blockIdx.x; v < 512; v += NB_)
      scanC_block(v, dtbc2, xz2b, xcvb2, A_log + (size_t)li * 2 * DI_ * N_,
                  Dp + (size_t)li * 2 * DI_, Hinit, ybf2, Bs, Cs);
    gsync(bar, bi++);
    // P9: out-proj + residual (256 tiles)
    for (int t = blockIdx.x; t < 256; t += NB_)
      gemm64_tile(ybf2, nullptr, outWb + (size_t)li * 2 * DH_ * DI_,
                  (long)DH_ * DI_, nullptr, 0, u_f, u_f, nullptr, 256, DI_, 0,
                  (t >> 2) * 64, (t & 3) * 64, As, (short(*)[40])Ws);
    gsync(bar, bi++);
    // P10: op + concat(+flip) (256 tiles)
    for (int t = blockIdx.x; t < 256; t += NB_)
      gemm64_tile(nullptr, u_f, opWb + (size_t)li * D_ * D_, 0,
                  opB + (size_t)li * D_, 0, nullptr, h_cur, xb, 512, D_, 4,
                  (t >> 3) * 64, (t & 7) * 64, As, (short(*)[40])Ws);
    gsync(bar, bi++);
  }
  // P11: final LN (2048 rows)
  for (int row = blockIdx.x; row < M_; row += NB_)
    ln_row(row, h_cur, fln_g, fln_b, 0, (void*)out, D_, 0, r1, r2);
}

// ---------------------------------------------------------------------------
extern "C" void kernel_launch(void* const* d_in, const int* in_sizes, int n_in,
                              void* d_out, int out_size, void* d_ws, size_t ws_size,
                              hipStream_t stream) {
  const float* x     = (const float*)d_in[0];
  const float* ln_g  = (const float*)d_in[1];
  const float* ln_b  = (const float*)d_in[2];
  const float* inW   = (const float*)d_in[3];
  const float* convW = (const float*)d_in[4];
  const float* convB = (const float*)d_in[5];
  const float* xprojW= (const float*)d_in[6];
  const float* dtW   = (const float*)d_in[7];
  const float* dtB   = (const float*)d_in[8];
  const float* A_log = (const float*)d_in[9];
  const float* Dp    = (const float*)d_in[10];
  const float* outW  = (const float*)d_in[11];
  const float* ipW   = (const float*)d_in[12];
  const float* ipB   = (const float*)d_in[13];
  const float* opW   = (const float*)d_in[14];
  const float* opB   = (const float*)d_in[15];
  const float* fln_g = (const float*)d_in[16];
  const float* fln_b = (const float*)d_in[17];
  float* out = (float*)d_out;

  // ---- workspace: barrier slots first (32 x 4KB = 128KB), then buffers ----
  unsigned* bar = (unsigned*)d_ws;
  float* w = (float*)((char*)d_ws + 131072);
  float* h_cur = w;  w += (size_t)M_ * D_;
  float* u_f   = w;  w += (size_t)M2_ * DH_;
  float* dtbc2 = w;  w += (size_t)M2_ * NCP_;
  float* Pbuf  = w;  w += (size_t)4 * CN_ * 16 * 512;
  float* hend  = w;  w += (size_t)4 * CN_ * 16 * 512;
  bf16* bw = (bf16*)w;
  bf16* xz2b  = bw;  bw += (size_t)M2_ * 1024;
  bf16* xb    = bw;  bw += (size_t)M_ * D_;
  bf16* xnb2  = bw;  bw += (size_t)M2_ * DH_;
  bf16* xcvb2 = bw;  bw += (size_t)M2_ * DI_;
  bf16* ybf2  = bw;  bw += (size_t)M2_ * DI_;
  bf16* ipWb  = bw;  bw += (size_t)IPW_N;
  bf16* inWb  = bw;  bw += (size_t)INW_N;
  bf16* outWb = bw;  bw += (size_t)OUTW_N;
  bf16* opWb  = bw;  bw += (size_t)OPW_N;
  bf16* Wcomb = bw;  bw += (size_t)4 * NCP_ * 512;

  hipMemsetAsync(bar, 0, 131072, stream);
  k_mega<<<NB_, 256, 0, stream>>>(
      x, ln_g, ln_b, inW, convW, convB, xprojW, dtW, dtB, A_log, Dp, outW,
      ipW, ipB, opW, opB, fln_g, fln_b, out,
      h_cur, u_f, dtbc2, Pbuf, hend,
      xz2b, xb, xnb2, xcvb2, ybf2,
      ipWb, inWb, outWb, opWb, Wcomb, bar);
}

// Round 14
// 330.904 us; speedup vs baseline: 7.0210x; 7.0210x over previous
//
#include <hip/hip_runtime.h>
#include <hip/hip_bf16.h>
#include <math.h>

typedef __hip_bfloat16 bf16;
typedef __attribute__((ext_vector_type(8))) short s8v;   // 8 bf16 (4 VGPRs)
typedef __attribute__((ext_vector_type(4))) float f4v;   // MFMA accumulator

// Problem constants (MambaEncoder: L=2, B=2, S=1024, D=512) — f32 in, f32 out.
#define B_ 2
#define S_ 1024
#define D_ 512
#define DH_ 256
#define DI_ 512
#define N_ 16
#define M_ 2048   // rows per direction; both dirs stacked -> M2_
#define M2_ 4096
#define T_ 16     // scan chunk length (register-preloaded)
#define CN_ 64    // chunks per sequence
#define NCP_ 640  // combined dt|B|C GEMM N (512 dt + 16 B + 16 C + 96 pad)

#define IPW_N (2*512*512)
#define INW_N (4*1024*256)
#define OUTW_N (4*256*512)
#define OPW_N (2*512*512)
#define PREP_R0 ((IPW_N+INW_N+OUTW_N+OPW_N)/4)   // weight casts, 4-wide
#define PREP_R1 (4*NCP_*512)                      // Wcomb elements
#define PREP_R2 ((M_*D_)/4)                       // x cast, 4-wide

__device__ __forceinline__ float softplus_fast(float v) {
  return (v > 15.f) ? v : __logf(1.f + __expf(v));
}

// ---------------------------------------------------------------------------
// Merged prep: weight casts + Wcomb build (dt folded through xproj) + x cast.
__global__ __launch_bounds__(256) void k_prep_all(
    const float* __restrict__ ipW, const float* __restrict__ inW,
    const float* __restrict__ outW, const float* __restrict__ opW,
    const float* __restrict__ dtW, const float* __restrict__ xprojW,
    const float* __restrict__ x,
    bf16* __restrict__ ipWb, bf16* __restrict__ inWb,
    bf16* __restrict__ outWb, bf16* __restrict__ opWb,
    bf16* __restrict__ Wcomb, bf16* __restrict__ xb) {
  int i = blockIdx.x * 256 + threadIdx.x;
  if (i < PREP_R0) {
    int e = i * 4;
    const float* s; bf16* dst; int off;
    if (e < IPW_N)                       { s = ipW;  dst = ipWb;  off = e; }
    else if (e < IPW_N + INW_N)          { s = inW;  dst = inWb;  off = e - IPW_N; }
    else if (e < IPW_N + INW_N + OUTW_N) { s = outW; dst = outWb; off = e - IPW_N - INW_N; }
    else                                 { s = opW;  dst = opWb;  off = e - IPW_N - INW_N - OUTW_N; }
    float4 v = *(const float4*)&s[off];
    dst[off + 0] = __float2bfloat16(v.x);
    dst[off + 1] = __float2bfloat16(v.y);
    dst[off + 2] = __float2bfloat16(v.z);
    dst[off + 3] = __float2bfloat16(v.w);
  } else if (i < PREP_R0 + PREP_R1) {
    int idx = i - PREP_R0;               // over 4*640*512
    int k = idx & 511;
    int row = (idx >> 9) % NCP_;
    int wi = idx / (NCP_ * 512);
    float v = 0.f;
    if (row < 512) {
      const float* dw = dtW + (size_t)wi * 512 * 16 + row * 16;
      const float* xw = xprojW + (size_t)wi * 48 * 512;
#pragma unroll
      for (int r = 0; r < 16; r++) v += dw[r] * xw[r * 512 + k];
    } else if (row < 544) {
      v = xprojW[(size_t)wi * 48 * 512 + (16 + row - 512) * 512 + k];
    }
    Wcomb[idx] = __float2bfloat16(v);
  } else if (i < PREP_R0 + PREP_R1 + PREP_R2) {
    int e = (i - PREP_R0 - PREP_R1) * 4;
    float4 v = *(const float4*)&x[e];
    xb[e + 0] = __float2bfloat16(v.x);
    xb[e + 1] = __float2bfloat16(v.y);
    xb[e + 2] = __float2bfloat16(v.z);
    xb[e + 3] = __float2bfloat16(v.w);
  }
}

// ---------------------------------------------------------------------------
// 64(M)x128(N) MFMA bf16 GEMM, reg-prefetch double-buffered staging.
// 4 waves, each owns a 64x32 strip. seg = bm>>11 (direction batching).
// ep1: Cb bf16 = acc                                   (in-proj -> xz)
// ep2: col<512 -> f32 softplus(acc+bias); else f32 acc (dtbc)
__global__ __launch_bounds__(256) void k_mgX(
    const bf16* __restrict__ A, const bf16* __restrict__ W, long Wstr,
    const float* __restrict__ bias, int bstr,
    float* __restrict__ C, bf16* __restrict__ Cb, int ldc, int K, int ep) {
  __shared__ short As[64][40];
  __shared__ short Ws[128][40];
  const int bm = blockIdx.y * 64, bn = blockIdx.x * 128;
  const int seg = bm >> 11;
  const bf16* Wp = W + (size_t)seg * Wstr;
  const float* bp = bias ? bias + (size_t)seg * bstr : nullptr;
  const int tid = threadIdx.x;
  const int wave = tid >> 6, lane = tid & 63;
  const int q = lane >> 4, l15 = lane & 15;
  const int wc = wave * 32;
  const int arow = tid >> 2, acol = (tid & 3) * 8;    // A staging: 16B/thread
  const int wrow = tid >> 1, wcol = (tid & 1) * 16;   // W staging: 32B/thread

  f4v acc[4][2];
#pragma unroll
  for (int s = 0; s < 4; s++)
#pragma unroll
    for (int j = 0; j < 2; j++) acc[s][j] = (f4v){0.f, 0.f, 0.f, 0.f};

  // prologue prefetch
  uint4 a_reg = *(const uint4*)&A[(size_t)(bm + arow) * K + acol];
  const bf16* wsrc0 = &Wp[(size_t)(bn + wrow) * K + wcol];
  uint4 w_reg0 = *(const uint4*)wsrc0;
  uint4 w_reg1 = *(const uint4*)(wsrc0 + 8);

  for (int k0 = 0; k0 < K; k0 += 32) {
    *(uint4*)&As[arow][acol] = a_reg;
    *(uint4*)&Ws[wrow][wcol] = w_reg0;
    *(uint4*)&Ws[wrow][wcol + 8] = w_reg1;
    __syncthreads();
    if (k0 + 32 < K) {   // prefetch next k-tile while MFMA runs
      a_reg = *(const uint4*)&A[(size_t)(bm + arow) * K + k0 + 32 + acol];
      const bf16* wsrc = &Wp[(size_t)(bn + wrow) * K + k0 + 32 + wcol];
      w_reg0 = *(const uint4*)wsrc;
      w_reg1 = *(const uint4*)(wsrc + 8);
    }
    s8v af[4], bf[2];
#pragma unroll
    for (int s = 0; s < 4; s++) af[s] = *(const s8v*)&As[s * 16 + l15][q * 8];
#pragma unroll
    for (int j = 0; j < 2; j++) bf[j] = *(const s8v*)&Ws[wc + j * 16 + l15][q * 8];
#pragma unroll
    for (int s = 0; s < 4; s++)
#pragma unroll
      for (int j = 0; j < 2; j++)
        acc[s][j] = __builtin_amdgcn_mfma_f32_16x16x32_bf16(af[s], bf[j], acc[s][j], 0, 0, 0);
    __syncthreads();
  }
#pragma unroll
  for (int j = 0; j < 2; j++) {
    int col = bn + wc + j * 16 + l15;
#pragma unroll
    for (int s = 0; s < 4; s++) {
      int row0 = bm + s * 16 + q * 4;
#pragma unroll
      for (int r = 0; r < 4; r++) {
        float v = acc[s][j][r];
        if (ep == 1) {
          Cb[(size_t)(row0 + r) * ldc + col] = __float2bfloat16(v);
        } else {  // ep2
          if (col < 512) v = softplus_fast(v + bp[col]);
          C[(size_t)(row0 + r) * ldc + col] = v;
        }
      }
    }
  }
}

// ---------------------------------------------------------------------------
// 64(M)x32(N) MFMA bf16 GEMM — high-occupancy tile for the small GEMMs
// (ip/out/op: 512 blocks = 2 blocks/CU). Reg-prefetch double-buffered.
// Wave w owns rows [w*16, w*16+16) x all 32 cols (2 MFMA : 3 ds_read).
// ep0: +bias(opt) +res(opt, may alias C) -> C f32
// ep3: ip+split: v=acc+bias; col<256 -> C[row*256+col];
//      col>=256 -> C[M_*256 + (row^1023)*256 + col-256]    (flip_S into u_b)
// ep4: op+concat: A staged from f32 u_f/u_b with flip+bf16 cvt;
//      v=acc+bias -> C f32 (h_cur) AND Cb bf16 (next-layer A)
__global__ __launch_bounds__(256) void k_mg32(
    const bf16* __restrict__ A, const float* __restrict__ Af,
    const bf16* __restrict__ W, long Wstr,
    const float* __restrict__ bias, int bstr,
    const float* res,
    float* C, bf16* Cb, int ldc, int K, int ep) {
  __shared__ short As[64][40];
  __shared__ short Ws[32][40];
  const int bm = blockIdx.y * 64, bn = blockIdx.x * 32;
  const int seg = bm >> 11;
  const bf16* Wp = W + (size_t)seg * Wstr;
  const float* bp = bias ? bias + (size_t)seg * bstr : nullptr;
  const int tid = threadIdx.x;
  const int wave = tid >> 6, lane = tid & 63;
  const int q = lane >> 4, l15 = lane & 15;
  const int trow = tid >> 2, tcol = (tid & 3) * 8;  // A: all 256 thr; W: tid<128
  const bool wact = tid < 128;

  f4v acc[2];
  acc[0] = (f4v){0.f, 0.f, 0.f, 0.f};
  acc[1] = (f4v){0.f, 0.f, 0.f, 0.f};

  // prologue prefetch
  uint4 a_reg, w_reg;
  {
    if (ep == 4) {
      int ck = tcol;
      const float* src = (ck < 256)
          ? Af + (size_t)(bm + trow) * 256 + ck
          : Af + (size_t)M_ * 256 + (size_t)((bm + trow) ^ 1023) * 256 + (ck - 256);
      float4 f0 = *(const float4*)src;
      float4 f1 = *(const float4*)(src + 4);
      float fv[8] = {f0.x, f0.y, f0.z, f0.w, f1.x, f1.y, f1.z, f1.w};
      short tmp[8];
#pragma unroll
      for (int i = 0; i < 8; i++) { bf16 b = __float2bfloat16(fv[i]); tmp[i] = *(short*)&b; }
      a_reg = *(uint4*)tmp;
    } else {
      a_reg = *(const uint4*)&A[(size_t)(bm + trow) * K + tcol];
    }
    if (wact) w_reg = *(const uint4*)&Wp[(size_t)(bn + trow) * K + tcol];
  }

  for (int k0 = 0; k0 < K; k0 += 32) {
    *(uint4*)&As[trow][tcol] = a_reg;
    if (wact) *(uint4*)&Ws[trow][tcol] = w_reg;
    __syncthreads();
    if (k0 + 32 < K) {
      int kn = k0 + 32;
      if (ep == 4) {
        int ck = kn + tcol;
        const float* src = (ck < 256)
            ? Af + (size_t)(bm + trow) * 256 + ck
            : Af + (size_t)M_ * 256 + (size_t)((bm + trow) ^ 1023) * 256 + (ck - 256);
        float4 f0 = *(const float4*)src;
        float4 f1 = *(const float4*)(src + 4);
        float fv[8] = {f0.x, f0.y, f0.z, f0.w, f1.x, f1.y, f1.z, f1.w};
        short tmp[8];
#pragma unroll
        for (int i = 0; i < 8; i++) { bf16 b = __float2bfloat16(fv[i]); tmp[i] = *(short*)&b; }
        a_reg = *(uint4*)tmp;
      } else {
        a_reg = *(const uint4*)&A[(size_t)(bm + trow) * K + kn + tcol];
      }
      if (wact) w_reg = *(const uint4*)&Wp[(size_t)(bn + trow) * K + kn + tcol];
    }
    s8v afrag = *(const s8v*)&As[wave * 16 + l15][q * 8];
    s8v bf0 = *(const s8v*)&Ws[l15][q * 8];
    s8v bf1 = *(const s8v*)&Ws[16 + l15][q * 8];
    acc[0] = __builtin_amdgcn_mfma_f32_16x16x32_bf16(afrag, bf0, acc[0], 0, 0, 0);
    acc[1] = __builtin_amdgcn_mfma_f32_16x16x32_bf16(afrag, bf1, acc[1], 0, 0, 0);
    __syncthreads();
  }
#pragma unroll
  for (int j = 0; j < 2; j++) {
    int col = bn + j * 16 + l15;
#pragma unroll
    for (int r = 0; r < 4; r++) {
      int row = bm + wave * 16 + q * 4 + r;
      float v = acc[j][r];
      if (ep == 0) {
        if (bp) v += bp[col];
        if (res) v += res[(size_t)row * ldc + col];
        C[(size_t)row * ldc + col] = v;
      } else if (ep == 3) {
        v += bp[col];
        if (col < 256)
          C[(size_t)row * 256 + col] = v;
        else
          C[(size_t)M_ * 256 + (size_t)(row ^ 1023) * 256 + (col - 256)] = v;
      } else {  // ep4
        v += bp[col];
        C[(size_t)row * 512 + col] = v;
        Cb[(size_t)row * 512 + col] = __float2bfloat16(v);
      }
    }
  }
}

// ---------------------------------------------------------------------------
// LayerNorm over last dim C (256 or 512). gstr: gamma/beta offset for rows>=M_.
__global__ __launch_bounds__(256) void k_ln(const float* __restrict__ X,
                                            const float* __restrict__ g,
                                            const float* __restrict__ bta,
                                            int gstr, void* __restrict__ Y,
                                            int C, int out_bf16) {
  const int row = blockIdx.x;
  const int sel = (row >= M_) ? gstr : 0;
  const float* xr = X + (size_t)row * C;
  const int tid = threadIdx.x;
  const int per = C >> 8;  // 1 or 2
  float vals[2];
  float sum = 0.f, sumsq = 0.f;
  for (int i = 0; i < per; i++) {
    float v = xr[tid + i * 256];
    vals[i] = v;
    sum += v;
    sumsq += v * v;
  }
#pragma unroll
  for (int off = 1; off < 64; off <<= 1) {
    sum += __shfl_xor(sum, off, 64);
    sumsq += __shfl_xor(sumsq, off, 64);
  }
  __shared__ float s1[4], s2[4];
  int wid = tid >> 6, lane = tid & 63;
  if (lane == 0) { s1[wid] = sum; s2[wid] = sumsq; }
  __syncthreads();
  if (tid == 0) {
    float a = 0.f, c2 = 0.f;
    for (int w = 0; w < 4; w++) { a += s1[w]; c2 += s2[w]; }
    s1[0] = a; s2[0] = c2;
  }
  __syncthreads();
  float mean = s1[0] / (float)C;
  float var = s2[0] / (float)C - mean * mean;
  float rstd = rsqrtf(var + 1e-5f);
  for (int i = 0; i < per; i++) {
    int c = tid + i * 256;
    float y = (vals[i] - mean) * rstd * g[sel + c] + bta[sel + c];
    if (out_bf16)
      ((bf16*)Y)[(size_t)row * C + c] = __float2bfloat16(y);
    else
      ((float*)Y)[(size_t)row * C + c] = y;
  }
}

// ---------------------------------------------------------------------------
// Causal depthwise conv (K=4) + SiLU, direction-batched. bf16 in (xz), bf16 out.
__global__ __launch_bounds__(256) void k_conv(const bf16* __restrict__ xz,
                                              const float* __restrict__ convW,
                                              const float* __restrict__ convB,
                                              bf16* __restrict__ outb) {
  int idx = blockIdx.x * 256 + threadIdx.x;  // over M2_*DI_
  if (idx >= M2_ * DI_) return;
  int d = idx & (DI_ - 1);
  int row = idx >> 9;          // 0..4095
  int seg = row >> 11;
  int t = row & (S_ - 1);
  const float* w = convW + seg * DI_ * 4;
  float acc = convB[seg * DI_ + d];
#pragma unroll
  for (int k = 0; k < 4; k++) {
    int dt_ = k - 3;
    if (t + dt_ >= 0)
      acc += w[d * 4 + k] * __bfloat162float(xz[(size_t)(row + dt_) * 1024 + d]);
  }
  float s = acc / (1.f + __expf(-acc));  // silu
  outb[idx] = __float2bfloat16(s);
}

// ---------------------------------------------------------------------------
// Chunked parallel scan, 4 sequences, T_=16 register-preloaded, CN_=64.
// dtbc (M2_,640) = [dt(512) | B(16) | C(16) | pad]. x from bf16 xcb.
__global__ __launch_bounds__(256) void k_scanA(
    const float* __restrict__ dtbc,
    const bf16* __restrict__ xcb,
    const float* __restrict__ A_log, // layer base; +dir*512*16
    float* __restrict__ P,           // [4][CN_][16][512]
    float* __restrict__ hend) {
  const int blk = blockIdx.x;        // 4*CN_*2 = 512
  const int half = blk & 1;
  const int c = (blk >> 1) & (CN_ - 1);
  const int s = blk >> 7;            // sequence 0..3
  const int dir = s >> 1;
  const int d = half * 256 + threadIdx.x;
  const int r0 = s * S_ + c * T_;
  __shared__ float Bs[T_][16];
  for (int i = threadIdx.x; i < T_ * 16; i += 256) {
    int t = i >> 4, n = i & 15;
    Bs[t][n] = dtbc[(size_t)(r0 + t) * NCP_ + 512 + n];
  }
  float Av[16];
#pragma unroll
  for (int n = 0; n < 16; n++) Av[n] = -__expf(A_log[dir * DI_ * 16 + d * 16 + n]);
  float dtv[T_], xv[T_];
#pragma unroll
  for (int t = 0; t < T_; t++) {
    size_t row = (size_t)(r0 + t);
    dtv[t] = dtbc[row * NCP_ + d];
    xv[t]  = __bfloat162float(xcb[row * 512 + d]);
  }
  __syncthreads();
  float h[16], Pr[16];
#pragma unroll
  for (int n = 0; n < 16; n++) { h[n] = 0.f; Pr[n] = 1.f; }
#pragma unroll
  for (int t = 0; t < T_; t++) {
    float dtx = dtv[t] * xv[t];
#pragma unroll
    for (int n = 0; n < 16; n++) {
      float a = __expf(dtv[t] * Av[n]);
      h[n] = a * h[n] + dtx * Bs[t][n];
      Pr[n] *= a;
    }
  }
  size_t base = (((size_t)s * CN_ + c) * 16) * 512 + d;
#pragma unroll
  for (int n = 0; n < 16; n++) {
    P[base + (size_t)n * 512] = Pr[n];
    hend[base + (size_t)n * 512] = h[n];
  }
}

// Pass B: serial prefix over chunks, one thread per (s,n,d). Hinit aliases P.
__global__ __launch_bounds__(256) void k_scanB(
    const float* __restrict__ P,
    const float* __restrict__ hend,
    float* __restrict__ Hinit) {
  int idx = blockIdx.x * 256 + threadIdx.x;  // over 4*16*512
  if (idx >= 4 * 16 * 512) return;
  int d = idx & 511;
  int n = (idx >> 9) & 15;
  int s = idx >> 13;
  float H = 0.f;
  for (int c = 0; c < CN_; c++) {
    size_t o = (((size_t)s * CN_ + c) * 16 + n) * 512 + d;
    float p = P[o];
    float he = hend[o];
    Hinit[o] = H;
    H = p * H + he;
  }
}

// Pass C: replay with true init; fused D-residual + silu(z); y -> bf16.
__global__ __launch_bounds__(256) void k_scanC(
    const float* __restrict__ dtbc,
    const bf16* __restrict__ xz,     // z at cols [512,1024), bf16
    const bf16* __restrict__ xcb,
    const float* __restrict__ A_log,
    const float* __restrict__ Dp,    // layer base; +dir*512
    const float* __restrict__ Hinit,
    bf16* __restrict__ ybf) {        // (M2_,512)
  const int blk = blockIdx.x;
  const int half = blk & 1;
  const int c = (blk >> 1) & (CN_ - 1);
  const int s = blk >> 7;
  const int dir = s >> 1;
  const int d = half * 256 + threadIdx.x;
  const int r0 = s * S_ + c * T_;
  __shared__ float Bs[T_][16], Cs[T_][16];
  for (int i = threadIdx.x; i < T_ * 16; i += 256) {
    int t = i >> 4, n = i & 15;
    size_t ro = (size_t)(r0 + t) * NCP_;
    Bs[t][n] = dtbc[ro + 512 + n];
    Cs[t][n] = dtbc[ro + 528 + n];
  }
  float Av[16];
#pragma unroll
  for (int n = 0; n < 16; n++) Av[n] = -__expf(A_log[dir * DI_ * 16 + d * 16 + n]);
  float Dd = Dp[dir * DI_ + d];
  float dtv[T_], xv[T_], zv[T_];
#pragma unroll
  for (int t = 0; t < T_; t++) {
    size_t row = (size_t)(r0 + t);
    dtv[t] = dtbc[row * NCP_ + d];
    xv[t]  = __bfloat162float(xcb[row * 512 + d]);
    zv[t]  = __bfloat162float(xz[row * 1024 + 512 + d]);
  }
  float h[16];
  size_t hbase = (((size_t)s * CN_ + c) * 16) * 512 + d;
#pragma unroll
  for (int n = 0; n < 16; n++) h[n] = Hinit[hbase + (size_t)n * 512];
  __syncthreads();
#pragma unroll
  for (int t = 0; t < T_; t++) {
    float dtx = dtv[t] * xv[t];
    float acc = 0.f;
#pragma unroll
    for (int n = 0; n < 16; n++) {
      float a = __expf(dtv[t] * Av[n]);
      h[n] = a * h[n] + dtx * Bs[t][n];
      acc += h[n] * Cs[t][n];
    }
    float sil = zv[t] / (1.f + __expf(-zv[t]));
    ybf[(size_t)(r0 + t) * 512 + d] = __float2bfloat16((acc + xv[t] * Dd) * sil);
  }
}

// ---------------------------------------------------------------------------
extern "C" void kernel_launch(void* const* d_in, const int* in_sizes, int n_in,
                              void* d_out, int out_size, void* d_ws, size_t ws_size,
                              hipStream_t stream) {
  const float* x     = (const float*)d_in[0];
  const float* ln_g  = (const float*)d_in[1];
  const float* ln_b  = (const float*)d_in[2];
  const float* inW   = (const float*)d_in[3];
  const float* convW = (const float*)d_in[4];
  const float* convB = (const float*)d_in[5];
  const float* xprojW= (const float*)d_in[6];
  const float* dtW   = (const float*)d_in[7];
  const float* dtB   = (const float*)d_in[8];
  const float* A_log = (const float*)d_in[9];
  const float* Dp    = (const float*)d_in[10];
  const float* outW  = (const float*)d_in[11];
  const float* ipW   = (const float*)d_in[12];
  const float* ipB   = (const float*)d_in[13];
  const float* opW   = (const float*)d_in[14];
  const float* opB   = (const float*)d_in[15];
  const float* fln_g = (const float*)d_in[16];
  const float* fln_b = (const float*)d_in[17];
  float* out = (float*)d_out;

  // ---- workspace ----
  float* w = (float*)d_ws;
  float* h_cur = w;  w += (size_t)M_ * D_;
  float* u_f   = w;  w += (size_t)M2_ * DH_;   // u_f rows [0,M), u_b rows [M,2M)
  float* dtbc2 = w;  w += (size_t)M2_ * NCP_;
  float* Pbuf  = w;  w += (size_t)4 * CN_ * 16 * 512;  // also Hinit
  float* hend  = w;  w += (size_t)4 * CN_ * 16 * 512;
  float* Hinit = Pbuf;
  bf16* bw = (bf16*)w;
  bf16* xz2b  = bw;  bw += (size_t)M2_ * 1024; // [xc | z] bf16, both dirs
  bf16* xb    = bw;  bw += (size_t)M_ * D_;
  bf16* xnb2  = bw;  bw += (size_t)M2_ * DH_;
  bf16* xcvb2 = bw;  bw += (size_t)M2_ * DI_;
  bf16* ybf2  = bw;  bw += (size_t)M2_ * DI_;
  bf16* ipWb  = bw;  bw += (size_t)IPW_N;
  bf16* inWb  = bw;  bw += (size_t)INW_N;
  bf16* outWb = bw;  bw += (size_t)OUTW_N;
  bf16* opWb  = bw;  bw += (size_t)OPW_N;
  bf16* Wcomb = bw;  bw += (size_t)4 * NCP_ * 512;

  // ---- merged prep (1 dispatch) ----
  int prep_threads = PREP_R0 + PREP_R1 + PREP_R2;
  k_prep_all<<<(prep_threads + 255) / 256, 256, 0, stream>>>(
      ipW, inW, outW, opW, dtW, xprojW, x,
      ipWb, inWb, outWb, opWb, Wcomb, xb);

  for (int li = 0; li < 2; li++) {
    // ip + fused split: xb @ ipW.T + ipB -> u_f / flipped u_b  (512 blocks)
    k_mg32<<<dim3(16, 32), 256, 0, stream>>>(
        xb, nullptr, ipWb + (size_t)li * D_ * D_, 0,
        ipB + (size_t)li * D_, 0, nullptr, u_f, nullptr, 256, D_, 3);
    // LN both dirs -> xnb2 bf16
    k_ln<<<M2_, 256, 0, stream>>>(u_f, ln_g + li * 2 * DH_, ln_b + li * 2 * DH_,
                                  DH_, (void*)xnb2, DH_, 1);
    // xz = xn @ inW.T  (both dirs) -> bf16, 64x128 tile (512 blocks)
    k_mgX<<<dim3(8, 64), 256, 0, stream>>>(
        xnb2, inWb + (size_t)li * 2 * 1024 * DH_, (long)1024 * DH_,
        nullptr, 0, nullptr, xz2b, 1024, DH_, 1);
    // conv + silu -> xcvb2 bf16
    k_conv<<<(M2_ * DI_ + 255) / 256, 256, 0, stream>>>(
        xz2b, convW + li * 2 * DI_ * 4, convB + li * 2 * DI_, xcvb2);
    // combined [softplus(dt) | B | C] GEMM, 64x128 tile, N padded to 640
    k_mgX<<<dim3(NCP_ / 128, 64), 256, 0, stream>>>(
        xcvb2, Wcomb + (size_t)li * 2 * NCP_ * 512, (long)NCP_ * 512,
        dtB + li * 2 * DI_, DI_, dtbc2, nullptr, NCP_, 512, 2);
    // chunked scan (4 sequences)
    k_scanA<<<4 * CN_ * 2, 256, 0, stream>>>(
        dtbc2, xcvb2, A_log + (size_t)li * 2 * DI_ * N_, Pbuf, hend);
    k_scanB<<<(4 * 16 * 512 + 255) / 256, 256, 0, stream>>>(Pbuf, hend, Hinit);
    k_scanC<<<4 * CN_ * 2, 256, 0, stream>>>(
        dtbc2, xz2b, xcvb2, A_log + (size_t)li * 2 * DI_ * N_,
        Dp + (size_t)li * 2 * DI_, Hinit, ybf2);
    // u += y @ outW.T  (both dirs, res alias; 512 blocks)
    k_mg32<<<dim3(8, 64), 256, 0, stream>>>(
        ybf2, nullptr, outWb + (size_t)li * 2 * DH_ * DI_, (long)DH_ * DI_,
        nullptr, 0, u_f, u_f, nullptr, 256, DI_, 0);
    // op + fused concat(+flip) + bias; h_cur f32 + xb bf16 (512 blocks)
    k_mg32<<<dim3(16, 32), 256, 0, stream>>>(
        nullptr, u_f, opWb + (size_t)li * D_ * D_, 0,
        opB + (size_t)li * D_, 0, nullptr, h_cur, xb, 512, D_, 4);
  }
  // final LN -> f32 out
  k_ln<<<M_, 256, 0, stream>>>(h_cur, fln_g, fln_b, 0, (void*)out, D_, 0);
}

// Round 15
// 319.128 us; speedup vs baseline: 7.2801x; 1.0369x over previous
//
#include <hip/hip_runtime.h>
#include <hip/hip_bf16.h>
#include <math.h>

typedef __hip_bfloat16 bf16;
typedef __attribute__((ext_vector_type(8))) short s8v;   // 8 bf16 (4 VGPRs)
typedef __attribute__((ext_vector_type(4))) float f4v;   // MFMA accumulator

// Problem constants (MambaEncoder: L=2, B=2, S=1024, D=512) — f32 in, f32 out.
#define B_ 2
#define S_ 1024
#define D_ 512
#define DH_ 256
#define DI_ 512
#define N_ 16
#define M_ 2048   // rows per direction; both dirs stacked -> M2_
#define M2_ 4096
#define T_ 16     // scan chunk length (register-preloaded)
#define CN_ 64    // chunks per sequence
#define NCP_ 640  // combined dt|B|C GEMM N (512 dt + 16 B + 16 C + 96 pad)

#define IPW_N (2*512*512)
#define INW_N (4*1024*256)
#define OUTW_N (4*256*512)
#define OPW_N (2*512*512)
#define PREP_R0 ((IPW_N+INW_N+OUTW_N+OPW_N)/4)   // weight casts, 4-wide
#define PREP_R1 (4*NCP_*512)                      // Wcomb elements
#define PREP_R2 ((M_*D_)/4)                       // x cast, 4-wide
#define PREP_R3 (4*DI_*N_)                        // Aexp = -exp(A_log)
#define PREP_TOT (PREP_R0+PREP_R1+PREP_R2+PREP_R3)

__device__ __forceinline__ float softplus_fast(float v) {
  return (v > 15.f) ? v : __logf(1.f + __expf(v));
}

// ---------------------------------------------------------------------------
// Merged prep: weight casts + Wcomb build + x cast + Aexp table.
__global__ __launch_bounds__(256) void k_prep_all(
    const float* __restrict__ ipW, const float* __restrict__ inW,
    const float* __restrict__ outW, const float* __restrict__ opW,
    const float* __restrict__ dtW, const float* __restrict__ xprojW,
    const float* __restrict__ x, const float* __restrict__ A_log,
    bf16* __restrict__ ipWb, bf16* __restrict__ inWb,
    bf16* __restrict__ outWb, bf16* __restrict__ opWb,
    bf16* __restrict__ Wcomb, bf16* __restrict__ xb,
    float* __restrict__ Aexp) {
  int i = blockIdx.x * 256 + threadIdx.x;
  if (i < PREP_R0) {
    int e = i * 4;
    const float* s; bf16* dst; int off;
    if (e < IPW_N)                       { s = ipW;  dst = ipWb;  off = e; }
    else if (e < IPW_N + INW_N)          { s = inW;  dst = inWb;  off = e - IPW_N; }
    else if (e < IPW_N + INW_N + OUTW_N) { s = outW; dst = outWb; off = e - IPW_N - INW_N; }
    else                                 { s = opW;  dst = opWb;  off = e - IPW_N - INW_N - OUTW_N; }
    float4 v = *(const float4*)&s[off];
    dst[off + 0] = __float2bfloat16(v.x);
    dst[off + 1] = __float2bfloat16(v.y);
    dst[off + 2] = __float2bfloat16(v.z);
    dst[off + 3] = __float2bfloat16(v.w);
  } else if (i < PREP_R0 + PREP_R1) {
    int idx = i - PREP_R0;               // over 4*640*512
    int k = idx & 511;
    int row = (idx >> 9) % NCP_;
    int wi = idx / (NCP_ * 512);
    float v = 0.f;
    if (row < 512) {
      const float* dw = dtW + (size_t)wi * 512 * 16 + row * 16;
      const float* xw = xprojW + (size_t)wi * 48 * 512;
#pragma unroll
      for (int r = 0; r < 16; r++) v += dw[r] * xw[r * 512 + k];
    } else if (row < 544) {
      v = xprojW[(size_t)wi * 48 * 512 + (16 + row - 512) * 512 + k];
    }
    Wcomb[idx] = __float2bfloat16(v);
  } else if (i < PREP_R0 + PREP_R1 + PREP_R2) {
    int e = (i - PREP_R0 - PREP_R1) * 4;
    float4 v = *(const float4*)&x[e];
    xb[e + 0] = __float2bfloat16(v.x);
    xb[e + 1] = __float2bfloat16(v.y);
    xb[e + 2] = __float2bfloat16(v.z);
    xb[e + 3] = __float2bfloat16(v.w);
  } else if (i < PREP_TOT) {
    int idx = i - PREP_R0 - PREP_R1 - PREP_R2;  // over 4*512*16
    Aexp[idx] = -__expf(A_log[idx]);
  }
}

// ---------------------------------------------------------------------------
// 64(M)x128(N) MFMA bf16 GEMM, reg-prefetch double-buffered staging.
// 4 waves, each owns a 64x32 strip. seg = bm>>11 (direction batching).
// ep1: Cb bf16 = acc  (in-proj -> xz)
__global__ __launch_bounds__(256) void k_mgX(
    const bf16* __restrict__ A, const bf16* __restrict__ W, long Wstr,
    bf16* __restrict__ Cb, int ldc, int K) {
  __shared__ short As[64][40];
  __shared__ short Ws[128][40];
  const int bm = blockIdx.y * 64, bn = blockIdx.x * 128;
  const int seg = bm >> 11;
  const bf16* Wp = W + (size_t)seg * Wstr;
  const int tid = threadIdx.x;
  const int wave = tid >> 6, lane = tid & 63;
  const int q = lane >> 4, l15 = lane & 15;
  const int wc = wave * 32;
  const int arow = tid >> 2, acol = (tid & 3) * 8;    // A staging: 16B/thread
  const int wrow = tid >> 1, wcol = (tid & 1) * 16;   // W staging: 32B/thread

  f4v acc[4][2];
#pragma unroll
  for (int s = 0; s < 4; s++)
#pragma unroll
    for (int j = 0; j < 2; j++) acc[s][j] = (f4v){0.f, 0.f, 0.f, 0.f};

  uint4 a_reg = *(const uint4*)&A[(size_t)(bm + arow) * K + acol];
  const bf16* wsrc0 = &Wp[(size_t)(bn + wrow) * K + wcol];
  uint4 w_reg0 = *(const uint4*)wsrc0;
  uint4 w_reg1 = *(const uint4*)(wsrc0 + 8);

  for (int k0 = 0; k0 < K; k0 += 32) {
    *(uint4*)&As[arow][acol] = a_reg;
    *(uint4*)&Ws[wrow][wcol] = w_reg0;
    *(uint4*)&Ws[wrow][wcol + 8] = w_reg1;
    __syncthreads();
    if (k0 + 32 < K) {
      a_reg = *(const uint4*)&A[(size_t)(bm + arow) * K + k0 + 32 + acol];
      const bf16* wsrc = &Wp[(size_t)(bn + wrow) * K + k0 + 32 + wcol];
      w_reg0 = *(const uint4*)wsrc;
      w_reg1 = *(const uint4*)(wsrc + 8);
    }
    s8v af[4], bf[2];
#pragma unroll
    for (int s = 0; s < 4; s++) af[s] = *(const s8v*)&As[s * 16 + l15][q * 8];
#pragma unroll
    for (int j = 0; j < 2; j++) bf[j] = *(const s8v*)&Ws[wc + j * 16 + l15][q * 8];
#pragma unroll
    for (int s = 0; s < 4; s++)
#pragma unroll
      for (int j = 0; j < 2; j++)
        acc[s][j] = __builtin_amdgcn_mfma_f32_16x16x32_bf16(af[s], bf[j], acc[s][j], 0, 0, 0);
    __syncthreads();
  }
#pragma unroll
  for (int j = 0; j < 2; j++) {
    int col = bn + wc + j * 16 + l15;
#pragma unroll
    for (int s = 0; s < 4; s++) {
      int row0 = bm + s * 16 + q * 4;
#pragma unroll
      for (int r = 0; r < 4; r++)
        Cb[(size_t)(row0 + r) * ldc + col] = __float2bfloat16(acc[s][j][r]);
    }
  }
}

// ---------------------------------------------------------------------------
// 64(M)x32(N) MFMA bf16 GEMM — high-occupancy tile. Reg-prefetch dbuf.
// Wave w owns rows [w*16, w*16+16) x all 32 cols.
// ep0: +bias(opt) +res(opt, may alias C) -> C f32
// ep2: col<512 -> f32 softplus(acc+bias[col]); else f32 acc   (dtbc)
// ep3: ip+split: v=acc+bias; col<256 -> C[row*256+col];
//      col>=256 -> C[M_*256 + (row^1023)*256 + col-256]    (flip_S into u_b)
// ep4: op+concat: A staged from f32 u_f/u_b with flip+bf16 cvt;
//      v=acc+bias -> C f32 (h_cur) AND Cb bf16 (next-layer A)
__global__ __launch_bounds__(256) void k_mg32(
    const bf16* __restrict__ A, const float* __restrict__ Af,
    const bf16* __restrict__ W, long Wstr,
    const float* __restrict__ bias, int bstr,
    const float* res,
    float* C, bf16* Cb, int ldc, int K, int ep) {
  __shared__ short As[64][40];
  __shared__ short Ws[32][40];
  const int bm = blockIdx.y * 64, bn = blockIdx.x * 32;
  const int seg = bm >> 11;
  const bf16* Wp = W + (size_t)seg * Wstr;
  const float* bp = bias ? bias + (size_t)seg * bstr : nullptr;
  const int tid = threadIdx.x;
  const int wave = tid >> 6, lane = tid & 63;
  const int q = lane >> 4, l15 = lane & 15;
  const int trow = tid >> 2, tcol = (tid & 3) * 8;
  const bool wact = tid < 128;

  f4v acc[2];
  acc[0] = (f4v){0.f, 0.f, 0.f, 0.f};
  acc[1] = (f4v){0.f, 0.f, 0.f, 0.f};

  uint4 a_reg, w_reg;
  {
    if (ep == 4) {
      int ck = tcol;
      const float* src = (ck < 256)
          ? Af + (size_t)(bm + trow) * 256 + ck
          : Af + (size_t)M_ * 256 + (size_t)((bm + trow) ^ 1023) * 256 + (ck - 256);
      float4 f0 = *(const float4*)src;
      float4 f1 = *(const float4*)(src + 4);
      float fv[8] = {f0.x, f0.y, f0.z, f0.w, f1.x, f1.y, f1.z, f1.w};
      short tmp[8];
#pragma unroll
      for (int i = 0; i < 8; i++) { bf16 b = __float2bfloat16(fv[i]); tmp[i] = *(short*)&b; }
      a_reg = *(uint4*)tmp;
    } else {
      a_reg = *(const uint4*)&A[(size_t)(bm + trow) * K + tcol];
    }
    if (wact) w_reg = *(const uint4*)&Wp[(size_t)(bn + trow) * K + tcol];
  }

  for (int k0 = 0; k0 < K; k0 += 32) {
    *(uint4*)&As[trow][tcol] = a_reg;
    if (wact) *(uint4*)&Ws[trow][tcol] = w_reg;
    __syncthreads();
    if (k0 + 32 < K) {
      int kn = k0 + 32;
      if (ep == 4) {
        int ck = kn + tcol;
        const float* src = (ck < 256)
            ? Af + (size_t)(bm + trow) * 256 + ck
            : Af + (size_t)M_ * 256 + (size_t)((bm + trow) ^ 1023) * 256 + (ck - 256);
        float4 f0 = *(const float4*)src;
        float4 f1 = *(const float4*)(src + 4);
        float fv[8] = {f0.x, f0.y, f0.z, f0.w, f1.x, f1.y, f1.z, f1.w};
        short tmp[8];
#pragma unroll
        for (int i = 0; i < 8; i++) { bf16 b = __float2bfloat16(fv[i]); tmp[i] = *(short*)&b; }
        a_reg = *(uint4*)tmp;
      } else {
        a_reg = *(const uint4*)&A[(size_t)(bm + trow) * K + kn + tcol];
      }
      if (wact) w_reg = *(const uint4*)&Wp[(size_t)(bn + trow) * K + kn + tcol];
    }
    s8v afrag = *(const s8v*)&As[wave * 16 + l15][q * 8];
    s8v bf0 = *(const s8v*)&Ws[l15][q * 8];
    s8v bf1 = *(const s8v*)&Ws[16 + l15][q * 8];
    acc[0] = __builtin_amdgcn_mfma_f32_16x16x32_bf16(afrag, bf0, acc[0], 0, 0, 0);
    acc[1] = __builtin_amdgcn_mfma_f32_16x16x32_bf16(afrag, bf1, acc[1], 0, 0, 0);
    __syncthreads();
  }
#pragma unroll
  for (int j = 0; j < 2; j++) {
    int col = bn + j * 16 + l15;
#pragma unroll
    for (int r = 0; r < 4; r++) {
      int row = bm + wave * 16 + q * 4 + r;
      float v = acc[j][r];
      if (ep == 0) {
        if (bp) v += bp[col];
        if (res) v += res[(size_t)row * ldc + col];
        C[(size_t)row * ldc + col] = v;
      } else if (ep == 2) {
        if (col < 512) v = softplus_fast(v + bp[col]);
        C[(size_t)row * ldc + col] = v;
      } else if (ep == 3) {
        v += bp[col];
        if (col < 256)
          C[(size_t)row * 256 + col] = v;
        else
          C[(size_t)M_ * 256 + (size_t)(row ^ 1023) * 256 + (col - 256)] = v;
      } else {  // ep4
        v += bp[col];
        C[(size_t)row * 512 + col] = v;
        Cb[(size_t)row * 512 + col] = __float2bfloat16(v);
      }
    }
  }
}

// ---------------------------------------------------------------------------
// LayerNorm over last dim C (256 or 512). gstr: gamma/beta offset for rows>=M_.
__global__ __launch_bounds__(256) void k_ln(const float* __restrict__ X,
                                            const float* __restrict__ g,
                                            const float* __restrict__ bta,
                                            int gstr, void* __restrict__ Y,
                                            int C, int out_bf16) {
  const int row = blockIdx.x;
  const int sel = (row >= M_) ? gstr : 0;
  const float* xr = X + (size_t)row * C;
  const int tid = threadIdx.x;
  const int per = C >> 8;  // 1 or 2
  float vals[2];
  float sum = 0.f, sumsq = 0.f;
  for (int i = 0; i < per; i++) {
    float v = xr[tid + i * 256];
    vals[i] = v;
    sum += v;
    sumsq += v * v;
  }
#pragma unroll
  for (int off = 1; off < 64; off <<= 1) {
    sum += __shfl_xor(sum, off, 64);
    sumsq += __shfl_xor(sumsq, off, 64);
  }
  __shared__ float s1[4], s2[4];
  int wid = tid >> 6, lane = tid & 63;
  if (lane == 0) { s1[wid] = sum; s2[wid] = sumsq; }
  __syncthreads();
  if (tid == 0) {
    float a = 0.f, c2 = 0.f;
    for (int w = 0; w < 4; w++) { a += s1[w]; c2 += s2[w]; }
    s1[0] = a; s2[0] = c2;
  }
  __syncthreads();
  float mean = s1[0] / (float)C;
  float var = s2[0] / (float)C - mean * mean;
  float rstd = rsqrtf(var + 1e-5f);
  for (int i = 0; i < per; i++) {
    int c = tid + i * 256;
    float y = (vals[i] - mean) * rstd * g[sel + c] + bta[sel + c];
    if (out_bf16)
      ((bf16*)Y)[(size_t)row * C + c] = __float2bfloat16(y);
    else
      ((float*)Y)[(size_t)row * C + c] = y;
  }
}

// ---------------------------------------------------------------------------
// Causal depthwise conv (K=4) + SiLU, direction-batched. bf16 in (xz), bf16 out.
__global__ __launch_bounds__(256) void k_conv(const bf16* __restrict__ xz,
                                              const float* __restrict__ convW,
                                              const float* __restrict__ convB,
                                              bf16* __restrict__ outb) {
  int idx = blockIdx.x * 256 + threadIdx.x;  // over M2_*DI_
  if (idx >= M2_ * DI_) return;
  int d = idx & (DI_ - 1);
  int row = idx >> 9;          // 0..4095
  int seg = row >> 11;
  int t = row & (S_ - 1);
  const float* w = convW + seg * DI_ * 4;
  float acc = convB[seg * DI_ + d];
#pragma unroll
  for (int k = 0; k < 4; k++) {
    int dt_ = k - 3;
    if (t + dt_ >= 0)
      acc += w[d * 4 + k] * __bfloat162float(xz[(size_t)(row + dt_) * 1024 + d]);
  }
  float s = acc / (1.f + __expf(-acc));  // silu
  outb[idx] = __float2bfloat16(s);
}

// ---------------------------------------------------------------------------
// Chunked parallel scan, 4 sequences, T_=16 register-preloaded, CN_=64.
// dtbc (M2_,640) = [dt(512) | B(16) | C(16) | pad]. x from bf16 xcb.
// Aexp: precomputed -exp(A_log), layer base passed in; +dir*512*16.
__global__ __launch_bounds__(256) void k_scanA(
    const float* __restrict__ dtbc,
    const bf16* __restrict__ xcb,
    const float* __restrict__ Aexp,
    float* __restrict__ P,           // [4][CN_][16][512]
    float* __restrict__ hend) {
  const int blk = blockIdx.x;        // 4*CN_*2 = 512
  const int half = blk & 1;
  const int c = (blk >> 1) & (CN_ - 1);
  const int s = blk >> 7;            // sequence 0..3
  const int dir = s >> 1;
  const int d = half * 256 + threadIdx.x;
  const int r0 = s * S_ + c * T_;
  __shared__ float Bs[T_][16];
  for (int i = threadIdx.x; i < T_ * 16; i += 256) {
    int t = i >> 4, n = i & 15;
    Bs[t][n] = dtbc[(size_t)(r0 + t) * NCP_ + 512 + n];
  }
  float Av[16];
#pragma unroll
  for (int n = 0; n < 16; n++) Av[n] = Aexp[dir * DI_ * 16 + d * 16 + n];
  float dtv[T_], xv[T_];
#pragma unroll
  for (int t = 0; t < T_; t++) {
    size_t row = (size_t)(r0 + t);
    dtv[t] = dtbc[row * NCP_ + d];
    xv[t]  = __bfloat162float(xcb[row * 512 + d]);
  }
  __syncthreads();
  float h[16], Pr[16];
#pragma unroll
  for (int n = 0; n < 16; n++) { h[n] = 0.f; Pr[n] = 1.f; }
#pragma unroll
  for (int t = 0; t < T_; t++) {
    float dtx = dtv[t] * xv[t];
#pragma unroll
    for (int n = 0; n < 16; n++) {
      float a = __expf(dtv[t] * Av[n]);
      h[n] = a * h[n] + dtx * Bs[t][n];
      Pr[n] *= a;
    }
  }
  size_t base = (((size_t)s * CN_ + c) * 16) * 512 + d;
#pragma unroll
  for (int n = 0; n < 16; n++) {
    P[base + (size_t)n * 512] = Pr[n];
    hend[base + (size_t)n * 512] = h[n];
  }
}

// Pass B: serial prefix over chunks, one thread per (s,n,d). Hinit aliases P.
__global__ __launch_bounds__(256) void k_scanB(
    const float* __restrict__ P,
    const float* __restrict__ hend,
    float* __restrict__ Hinit) {
  int idx = blockIdx.x * 256 + threadIdx.x;  // over 4*16*512
  if (idx >= 4 * 16 * 512) return;
  int d = idx & 511;
  int n = (idx >> 9) & 15;
  int s = idx >> 13;
  float H = 0.f;
  for (int c = 0; c < CN_; c++) {
    size_t o = (((size_t)s * CN_ + c) * 16 + n) * 512 + d;
    float p = P[o];
    float he = hend[o];
    Hinit[o] = H;
    H = p * H + he;
  }
}

// Pass C: replay with true init; fused D-residual + silu(z); y -> bf16.
__global__ __launch_bounds__(256) void k_scanC(
    const float* __restrict__ dtbc,
    const bf16* __restrict__ xz,     // z at cols [512,1024), bf16
    const bf16* __restrict__ xcb,
    const float* __restrict__ Aexp,
    const float* __restrict__ Dp,    // layer base; +dir*512
    const float* __restrict__ Hinit,
    bf16* __restrict__ ybf) {        // (M2_,512)
  const int blk = blockIdx.x;
  const int half = blk & 1;
  const int c = (blk >> 1) & (CN_ - 1);
  const int s = blk >> 7;
  const int dir = s >> 1;
  const int d = half * 256 + threadIdx.x;
  const int r0 = s * S_ + c * T_;
  __shared__ float Bs[T_][16], Cs[T_][16];
  for (int i = threadIdx.x; i < T_ * 16; i += 256) {
    int t = i >> 4, n = i & 15;
    size_t ro = (size_t)(r0 + t) * NCP_;
    Bs[t][n] = dtbc[ro + 512 + n];
    Cs[t][n] = dtbc[ro + 528 + n];
  }
  float Av[16];
#pragma unroll
  for (int n = 0; n < 16; n++) Av[n] = Aexp[dir * DI_ * 16 + d * 16 + n];
  float Dd = Dp[dir * DI_ + d];
  float dtv[T_], xv[T_], zv[T_];
#pragma unroll
  for (int t = 0; t < T_; t++) {
    size_t row = (size_t)(r0 + t);
    dtv[t] = dtbc[row * NCP_ + d];
    xv[t]  = __bfloat162float(xcb[row * 512 + d]);
    zv[t]  = __bfloat162float(xz[row * 1024 + 512 + d]);
  }
  float h[16];
  size_t hbase = (((size_t)s * CN_ + c) * 16) * 512 + d;
#pragma unroll
  for (int n = 0; n < 16; n++) h[n] = Hinit[hbase + (size_t)n * 512];
  __syncthreads();
#pragma unroll
  for (int t = 0; t < T_; t++) {
    float dtx = dtv[t] * xv[t];
    float acc = 0.f;
#pragma unroll
    for (int n = 0; n < 16; n++) {
      float a = __expf(dtv[t] * Av[n]);
      h[n] = a * h[n] + dtx * Bs[t][n];
      acc += h[n] * Cs[t][n];
    }
    float sil = zv[t] / (1.f + __expf(-zv[t]));
    ybf[(size_t)(r0 + t) * 512 + d] = __float2bfloat16((acc + xv[t] * Dd) * sil);
  }
}

// ---------------------------------------------------------------------------
extern "C" void kernel_launch(void* const* d_in, const int* in_sizes, int n_in,
                              void* d_out, int out_size, void* d_ws, size_t ws_size,
                              hipStream_t stream) {
  const float* x     = (const float*)d_in[0];
  const float* ln_g  = (const float*)d_in[1];
  const float* ln_b  = (const float*)d_in[2];
  const float* inW   = (const float*)d_in[3];
  const float* convW = (const float*)d_in[4];
  const float* convB = (const float*)d_in[5];
  const float* xprojW= (const float*)d_in[6];
  const float* dtW   = (const float*)d_in[7];
  const float* dtB   = (const float*)d_in[8];
  const float* A_log = (const float*)d_in[9];
  const float* Dp    = (const float*)d_in[10];
  const float* outW  = (const float*)d_in[11];
  const float* ipW   = (const float*)d_in[12];
  const float* ipB   = (const float*)d_in[13];
  const float* opW   = (const float*)d_in[14];
  const float* opB   = (const float*)d_in[15];
  const float* fln_g = (const float*)d_in[16];
  const float* fln_b = (const float*)d_in[17];
  float* out = (float*)d_out;

  // ---- workspace ----
  float* w = (float*)d_ws;
  float* h_cur = w;  w += (size_t)M_ * D_;
  float* u_f   = w;  w += (size_t)M2_ * DH_;   // u_f rows [0,M), u_b rows [M,2M)
  float* dtbc2 = w;  w += (size_t)M2_ * NCP_;
  float* Pbuf  = w;  w += (size_t)4 * CN_ * 16 * 512;  // also Hinit
  float* hend  = w;  w += (size_t)4 * CN_ * 16 * 512;
  float* Aexp  = w;  w += (size_t)4 * DI_ * N_;
  float* Hinit = Pbuf;
  bf16* bw = (bf16*)w;
  bf16* xz2b  = bw;  bw += (size_t)M2_ * 1024; // [xc | z] bf16, both dirs
  bf16* xb    = bw;  bw += (size_t)M_ * D_;
  bf16* xnb2  = bw;  bw += (size_t)M2_ * DH_;
  bf16* xcvb2 = bw;  bw += (size_t)M2_ * DI_;
  bf16* ybf2  = bw;  bw += (size_t)M2_ * DI_;
  bf16* ipWb  = bw;  bw += (size_t)IPW_N;
  bf16* inWb  = bw;  bw += (size_t)INW_N;
  bf16* outWb = bw;  bw += (size_t)OUTW_N;
  bf16* opWb  = bw;  bw += (size_t)OPW_N;
  bf16* Wcomb = bw;  bw += (size_t)4 * NCP_ * 512;

  // ---- merged prep (1 dispatch) ----
  k_prep_all<<<(PREP_TOT + 255) / 256, 256, 0, stream>>>(
      ipW, inW, outW, opW, dtW, xprojW, x, A_log,
      ipWb, inWb, outWb, opWb, Wcomb, xb, Aexp);

  for (int li = 0; li < 2; li++) {
    // ip + fused split: xb @ ipW.T + ipB -> u_f / flipped u_b  (512 blocks)
    k_mg32<<<dim3(16, 32), 256, 0, stream>>>(
        xb, nullptr, ipWb + (size_t)li * D_ * D_, 0,
        ipB + (size_t)li * D_, 0, nullptr, u_f, nullptr, 256, D_, 3);
    // LN both dirs -> xnb2 bf16
    k_ln<<<M2_, 256, 0, stream>>>(u_f, ln_g + li * 2 * DH_, ln_b + li * 2 * DH_,
                                  DH_, (void*)xnb2, DH_, 1);
    // xz = xn @ inW.T  (both dirs) -> bf16, 64x128 tile (512 blocks)
    k_mgX<<<dim3(8, 64), 256, 0, stream>>>(
        xnb2, inWb + (size_t)li * 2 * 1024 * DH_, (long)1024 * DH_,
        xz2b, 1024, DH_);
    // conv + silu -> xcvb2 bf16
    k_conv<<<(M2_ * DI_ + 255) / 256, 256, 0, stream>>>(
        xz2b, convW + li * 2 * DI_ * 4, convB + li * 2 * DI_, xcvb2);
    // combined [softplus(dt) | B | C] GEMM, 64x32 tile (1280 blocks, balanced)
    k_mg32<<<dim3(NCP_ / 32, 64), 256, 0, stream>>>(
        xcvb2, nullptr, Wcomb + (size_t)li * 2 * NCP_ * 512, (long)NCP_ * 512,
        dtB + li * 2 * DI_, DI_, nullptr, dtbc2, nullptr, NCP_, 512, 2);
    // chunked scan (4 sequences)
    k_scanA<<<4 * CN_ * 2, 256, 0, stream>>>(
        dtbc2, xcvb2, Aexp + (size_t)li * 2 * DI_ * N_, Pbuf, hend);
    k_scanB<<<(4 * 16 * 512 + 255) / 256, 256, 0, stream>>>(Pbuf, hend, Hinit);
    k_scanC<<<4 * CN_ * 2, 256, 0, stream>>>(
        dtbc2, xz2b, xcvb2, Aexp + (size_t)li * 2 * DI_ * N_,
        Dp + (size_t)li * 2 * DI_, Hinit, ybf2);
    // u += y @ outW.T  (both dirs, res alias; 512 blocks)
    k_mg32<<<dim3(8, 64), 256, 0, stream>>>(
        ybf2, nullptr, outWb + (size_t)li * 2 * DH_ * DI_, (long)DH_ * DI_,
        nullptr, 0, u_f, u_f, nullptr, 256, DI_, 0);
    // op + fused concat(+flip) + bias; h_cur f32 + xb bf16 (512 blocks)
    k_mg32<<<dim3(16, 32), 256, 0, stream>>>(
        nullptr, u_f, opWb + (size_t)li * D_ * D_, 0,
        opB + (size_t)li * D_, 0, nullptr, h_cur, xb, 512, D_, 4);
  }
  // final LN -> f32 out
  k_ln<<<M_, 256, 0, stream>>>(h_cur, fln_g, fln_b, 0, (void*)out, D_, 0);
}